// Round 6
// baseline (352.831 us; speedup 1.0000x reference)
//
#include <hip/hip_runtime.h>
#include <hip/hip_bf16.h>

#define B_ROWS 16384
#define D_DIM  512
#define C_DIM  4096
#define H_DIM  1024

typedef __attribute__((ext_vector_type(8))) short  bf16x8;
typedef __attribute__((ext_vector_type(8))) unsigned short u16x8;
typedef __attribute__((ext_vector_type(4))) float  f32x4;

#define GLB __attribute__((address_space(1)))
#define LDS __attribute__((address_space(3)))

#define MFMA(d, va, vb) d = __builtin_amdgcn_mfma_f32_16x16x32_bf16(va, vb, d, 0, 0, 0)

__device__ __forceinline__ unsigned short f2bf(float f) {
    unsigned int u = __float_as_uint(f);
    unsigned int r = (u + 0x7FFFu + ((u >> 16) & 1u)) >> 16;   // RNE
    return (unsigned short)r;
}

__device__ __forceinline__ void async16(const void* g, void* l) {
    __builtin_amdgcn_global_load_lds((const GLB unsigned int*)g,
                                     (LDS unsigned int*)l, 16, 0, 0);
}

__device__ __forceinline__ float read_sigma(const int* p) {
    int v = *p;
    if (v >= 1 && v < (1 << 20)) return (float)v;   // stored as int
    return __int_as_float(v);                        // stored as float bits
}

// ---- prep: convert 512-col f32 rows to bf16 + row sum of squares (4 rows/block) ----
__global__ __launch_bounds__(256) void prep_rows(const float* __restrict__ in,
                                                 unsigned short* __restrict__ outb,
                                                 float* __restrict__ out2) {
    int row  = blockIdx.x * 4 + (threadIdx.x >> 6);
    int lane = threadIdx.x & 63;
    const float4* p = (const float4*)(in + (size_t)row * D_DIM) + lane * 2;
    float4 a = p[0], b = p[1];
    float s = a.x*a.x + a.y*a.y + a.z*a.z + a.w*a.w
            + b.x*b.x + b.y*b.y + b.z*b.z + b.w*b.w;
    u16x8 o = { f2bf(a.x), f2bf(a.y), f2bf(a.z), f2bf(a.w),
                f2bf(b.x), f2bf(b.y), f2bf(b.z), f2bf(b.w) };
    *(u16x8*)(outb + (size_t)row * D_DIM + lane * 8) = o;
#pragma unroll
    for (int off = 32; off; off >>= 1) s += __shfl_down(s, off, 64);
    if (lane == 0) out2[row] = s;
}

// ---- prep: plain f32 -> bf16 convert (8 elems/thread) ----
__global__ __launch_bounds__(256) void conv_bf16(const float* __restrict__ in,
                                                 unsigned short* __restrict__ outb,
                                                 int n8) {
    int i = blockIdx.x * 256 + threadIdx.x;
    if (i >= n8) return;
    const float4* p = (const float4*)in + (size_t)i * 2;
    float4 a = p[0], b = p[1];
    u16x8 o = { f2bf(a.x), f2bf(a.y), f2bf(a.z), f2bf(a.w),
                f2bf(b.x), f2bf(b.y), f2bf(b.z), f2bf(b.w) };
    *((u16x8*)outb + i) = o;
}

// ---- stage a 128x64 bf16 half-tile (512 threads, 2 gload_lds each) ----
// linear LDS dest; inverse swizzle on SOURCE; read-side chunk swizzle c^(r&7)
__device__ __forceinline__ void stage_half(const unsigned short* __restrict__ g,
                                           int ld, int rowBase, int k0,
                                           unsigned short* lds, int tid) {
#pragma unroll
    for (int i = 0; i < 2; i++) {
        int idx = i * 512 + tid;          // 16B-chunk index, 0..1023
        int row = idx >> 3;               // 8 chunks per 64-elem row
        int cc  = (idx & 7) ^ (row & 7);  // inverse swizzle on SOURCE
        const unsigned short* src = g + (size_t)(rowBase + row) * ld + k0 + cc * 8;
        unsigned short* dst = lds + (i * 512 + (tid & 448)) * 8; // wave-uniform base
        async16(src, dst);
    }
}

__device__ __forceinline__ bf16x8 frag(const unsigned short* T, int r, int kc) {
    return *(const bf16x8*)(T + r * 64 + ((kc ^ (r & 7)) << 3));
}

// ---- one K-tile (BK=64): 3-barrier structure.
//  W1: read a[m0-3]+b[n0-3] (16 ds_read), MFMA m0-3 x n0-3 (32)   | BAR1
//  W2: stage B(t+2), read a[m4-7] (8),   MFMA m4-7 x n0-3 (32)   | BAR2
//  W3: stage A(t+2), vmcnt(8) (or 0 on tail)                      | BAR3
// Hazards: BAR1 legalizes stage-B (all waves consumed B frags);
// BAR2 legalizes stage-A; vmcnt+BAR3 publishes tile t-1's stages
// (read by tile t+1). Stage targets are 2 tiles ahead, same parity.
__device__ __forceinline__ void ktile(unsigned short* __restrict__ Ap,
                                      unsigned short* __restrict__ Bp,
                                      const unsigned short* __restrict__ gA, int lda, int aRow0,
                                      const unsigned short* __restrict__ gB, int ldb, int bRow0,
                                      int kNext, bool doStage,
                                      f32x4 (&acc)[8][4], int tid, int l, int AR, int BC) {
    const int lr = l & 15, hi = l >> 4;
    bf16x8 a[4][2], b[4][2];

    // ---- W1 ----
#pragma unroll
    for (int m = 0; m < 4; m++) { int r = AR + m * 16 + lr;
#pragma unroll
        for (int kk = 0; kk < 2; kk++) a[m][kk] = frag(Ap, r, kk * 4 + hi); }
#pragma unroll
    for (int n = 0; n < 4; n++) { int r = BC + n * 16 + lr;
#pragma unroll
        for (int kk = 0; kk < 2; kk++) b[n][kk] = frag(Bp, r, kk * 4 + hi); }
    __builtin_amdgcn_s_setprio(1);
#pragma unroll
    for (int kk = 0; kk < 2; kk++)
#pragma unroll
        for (int m = 0; m < 4; m++)
#pragma unroll
            for (int n = 0; n < 4; n++) MFMA(acc[m][n], a[m][kk], b[n][kk]);
    __builtin_amdgcn_s_setprio(0);
    __builtin_amdgcn_s_barrier();                      // BAR1: all B reads consumed

    // ---- W2 ----
    if (doStage) {
        stage_half(gB, ldb, bRow0,       kNext, Bp,        tid);
        stage_half(gB, ldb, bRow0 + 128, kNext, Bp + 8192, tid);
    }
#pragma unroll
    for (int m = 0; m < 4; m++) { int r = AR + (m + 4) * 16 + lr;
#pragma unroll
        for (int kk = 0; kk < 2; kk++) a[m][kk] = frag(Ap, r, kk * 4 + hi); }
    __builtin_amdgcn_s_setprio(1);
#pragma unroll
    for (int kk = 0; kk < 2; kk++)
#pragma unroll
        for (int m = 0; m < 4; m++)
#pragma unroll
            for (int n = 0; n < 4; n++) MFMA(acc[4 + m][n], a[m][kk], b[n][kk]);
    __builtin_amdgcn_s_setprio(0);
    __builtin_amdgcn_s_barrier();                      // BAR2: all A reads consumed

    // ---- W3 ----
    if (doStage) {
        stage_half(gA, lda, aRow0,       kNext, Ap,        tid);
        stage_half(gA, lda, aRow0 + 128, kNext, Ap + 8192, tid);
        asm volatile("s_waitcnt vmcnt(8)" ::: "memory");   // t-1's 8 landed; t's 8 fly
    } else {
        asm volatile("s_waitcnt vmcnt(0)" ::: "memory");   // tail: drain everything
    }
    __builtin_amdgcn_s_barrier();                      // BAR3: staged buffer published
}

__device__ __forceinline__ void gemm_core(const unsigned short* __restrict__ gA, int lda, int aRow0,
                                          const unsigned short* __restrict__ gB, int ldb, int bRow0,
                                          int nt, f32x4 (&acc)[8][4],
                                          unsigned short (&As)[2][16384],
                                          unsigned short (&Bs)[2][16384],
                                          int tid, int l, int AR, int BC) {
    // prologue: stage K-tiles 0 and 1 (order matters for vmcnt aging)
    stage_half(gA, lda, aRow0,       0,  As[0],        tid);
    stage_half(gA, lda, aRow0 + 128, 0,  As[0] + 8192, tid);
    stage_half(gB, ldb, bRow0,       0,  Bs[0],        tid);
    stage_half(gB, ldb, bRow0 + 128, 0,  Bs[0] + 8192, tid);
    stage_half(gA, lda, aRow0,       64, As[1],        tid);
    stage_half(gA, lda, aRow0 + 128, 64, As[1] + 8192, tid);
    stage_half(gB, ldb, bRow0,       64, Bs[1],        tid);
    stage_half(gB, ldb, bRow0 + 128, 64, Bs[1] + 8192, tid);
    asm volatile("s_waitcnt vmcnt(8)" ::: "memory");   // tile0 landed; tile1 in flight
    __builtin_amdgcn_s_barrier();

    for (int t = 0; t < nt; t += 2) {
        ktile(As[0], Bs[0], gA, lda, aRow0, gB, ldb, bRow0, (t + 2) * 64, t + 2 < nt,
              acc, tid, l, AR, BC);
        ktile(As[1], Bs[1], gA, lda, aRow0, gB, ldb, bRow0, (t + 3) * 64, t + 3 < nt,
              acc, tid, l, AR, BC);
    }
}

// ---- GEMM1: xc = x @ centers^T ; epilogue -> phi bf16 ----
__global__ __launch_bounds__(512) void gemm1_kernel(const unsigned short* __restrict__ xb,
                                                    const unsigned short* __restrict__ cb,
                                                    const float* __restrict__ x2,
                                                    const float* __restrict__ c2,
                                                    const int* __restrict__ sigp,
                                                    unsigned short* __restrict__ phi) {
    __shared__ unsigned short As[2][16384];
    __shared__ unsigned short Bs[2][16384];
    int tid = threadIdx.x;
    // XCD-chunked swizzle (nwg = 1024, %8 == 0)
    int nwg = gridDim.x, cpx = nwg >> 3, bid = blockIdx.x;
    int nb = (bid & 7) * cpx + (bid >> 3);
    const int nbx = C_DIM / 256;
    int aRow0 = (nb / nbx) * 256, bRow0 = (nb % nbx) * 256;
    int l = tid & 63, wid = tid >> 6;
    int AR = (wid >> 2) * 128, BC = (wid & 3) * 64;

    f32x4 acc[8][4] = {};
    gemm_core(xb, D_DIM, aRow0, cb, D_DIM, bRow0, D_DIM / 64, acc, As, Bs, tid, l, AR, BC);

    float inv2s = 0.5f / read_sigma(sigp);
    int lr = l & 15, hi = l >> 4;
#pragma unroll
    for (int m = 0; m < 8; m++) {
#pragma unroll
        for (int j = 0; j < 4; j++) {
            int row = aRow0 + AR + m * 16 + hi * 4 + j;
            float xr = x2[row];
#pragma unroll
            for (int n = 0; n < 4; n++) {
                int col = bRow0 + BC + n * 16 + lr;
                float d2 = fmaxf(xr + c2[col] - 2.0f * acc[m][n][j], 0.0f);
                float ph = __expf(-__builtin_sqrtf(d2) * inv2s);
                phi[(size_t)row * C_DIM + col] = f2bf(ph);
            }
        }
    }
}

// ---- GEMM2: out = sigmoid(phi @ W1^T + b1) ----
__global__ __launch_bounds__(512) void gemm2_kernel(const unsigned short* __restrict__ phi,
                                                    const unsigned short* __restrict__ wb,
                                                    const float* __restrict__ b1,
                                                    float* __restrict__ out) {
    __shared__ unsigned short As[2][16384];
    __shared__ unsigned short Bs[2][16384];
    int tid = threadIdx.x;
    // XCD-chunked swizzle (nwg = 256, %8 == 0)
    int nwg = gridDim.x, cpx = nwg >> 3, bid = blockIdx.x;
    int nb = (bid & 7) * cpx + (bid >> 3);
    const int nbx = H_DIM / 256;
    int aRow0 = (nb / nbx) * 256, bRow0 = (nb % nbx) * 256;
    int l = tid & 63, wid = tid >> 6;
    int AR = (wid >> 2) * 128, BC = (wid & 3) * 64;

    f32x4 acc[8][4] = {};
    gemm_core(phi, C_DIM, aRow0, wb, C_DIM, bRow0, C_DIM / 64, acc, As, Bs, tid, l, AR, BC);

    int lr = l & 15, hi = l >> 4;
#pragma unroll
    for (int m = 0; m < 8; m++) {
#pragma unroll
        for (int j = 0; j < 4; j++) {
            int row = aRow0 + AR + m * 16 + hi * 4 + j;
#pragma unroll
            for (int n = 0; n < 4; n++) {
                int col = bRow0 + BC + n * 16 + lr;
                float z = acc[m][n][j] + b1[col];
                out[(size_t)row * H_DIM + col] = 1.0f / (1.0f + __expf(-z));
            }
        }
    }
}

extern "C" void kernel_launch(void* const* d_in, const int* in_sizes, int n_in,
                              void* d_out, int out_size, void* d_ws, size_t ws_size,
                              hipStream_t stream) {
    const float* x       = (const float*)d_in[0];
    const float* centers = (const float*)d_in[1];
    const float* W1      = (const float*)d_in[2];
    const float* b1      = (const float*)d_in[3];
    const int*   sig     = (const int*)d_in[4];
    float* out = (float*)d_out;

    char* ws = (char*)d_ws;
    unsigned short* phi = (unsigned short*)(ws);                 // 16384*4096*2 = 134217728
    unsigned short* xb  = (unsigned short*)(ws + 134217728);     // 16384*512*2  = 16777216
    unsigned short* cb  = (unsigned short*)(ws + 150994944);     // 4096*512*2   = 4194304
    unsigned short* wb  = (unsigned short*)(ws + 155189248);     // 1024*4096*2  = 8388608
    float* x2 = (float*)(ws + 163577856);                        // 16384*4
    float* c2 = (float*)(ws + 163643392);                        // 4096*4

    prep_rows<<<B_ROWS / 4, 256, 0, stream>>>(x, xb, x2);
    prep_rows<<<C_DIM / 4, 256, 0, stream>>>(centers, cb, c2);
    conv_bf16<<<(H_DIM * C_DIM / 8 + 255) / 256, 256, 0, stream>>>(W1, wb, H_DIM * C_DIM / 8);

    gemm1_kernel<<<(B_ROWS / 256) * (C_DIM / 256), 512, 0, stream>>>(xb, cb, x2, c2, sig, phi);
    gemm2_kernel<<<(B_ROWS / 256) * (H_DIM / 256), 512, 0, stream>>>(phi, wb, b1, out);
}

// Round 14
// 344.650 us; speedup vs baseline: 1.0237x; 1.0237x over previous
//
#include <hip/hip_runtime.h>
#include <hip/hip_bf16.h>

#define B_ROWS 16384
#define D_DIM  512
#define C_DIM  4096
#define H_DIM  1024

typedef __attribute__((ext_vector_type(8))) short  bf16x8;
typedef __attribute__((ext_vector_type(8))) unsigned short u16x8;
typedef __attribute__((ext_vector_type(4))) float  f32x4;

#define GLB __attribute__((address_space(1)))
#define LDS __attribute__((address_space(3)))

#define MFMA(d, va, vb) d = __builtin_amdgcn_mfma_f32_16x16x32_bf16(va, vb, d, 0, 0, 0)
#define BAR()   __builtin_amdgcn_s_barrier()
#define LGKM0() asm volatile("s_waitcnt lgkmcnt(0)" ::: "memory")

__device__ __forceinline__ unsigned short f2bf(float f) {
    unsigned int u = __float_as_uint(f);
    unsigned int r = (u + 0x7FFFu + ((u >> 16) & 1u)) >> 16;   // RNE
    return (unsigned short)r;
}

__device__ __forceinline__ void async16(const void* g, void* l) {
    __builtin_amdgcn_global_load_lds((const GLB unsigned int*)g,
                                     (LDS unsigned int*)l, 16, 0, 0);
}

__device__ __forceinline__ float read_sigma(const int* p) {
    int v = *p;
    if (v >= 1 && v < (1 << 20)) return (float)v;   // stored as int
    return __int_as_float(v);                        // stored as float bits
}

// ---- prep: convert 512-col f32 rows to bf16 + row sum of squares (4 rows/block) ----
__global__ __launch_bounds__(256) void prep_rows(const float* __restrict__ in,
                                                 unsigned short* __restrict__ outb,
                                                 float* __restrict__ out2) {
    int row  = blockIdx.x * 4 + (threadIdx.x >> 6);
    int lane = threadIdx.x & 63;
    const float4* p = (const float4*)(in + (size_t)row * D_DIM) + lane * 2;
    float4 a = p[0], b = p[1];
    float s = a.x*a.x + a.y*a.y + a.z*a.z + a.w*a.w
            + b.x*b.x + b.y*b.y + b.z*b.z + b.w*b.w;
    u16x8 o = { f2bf(a.x), f2bf(a.y), f2bf(a.z), f2bf(a.w),
                f2bf(b.x), f2bf(b.y), f2bf(b.z), f2bf(b.w) };
    *(u16x8*)(outb + (size_t)row * D_DIM + lane * 8) = o;
#pragma unroll
    for (int off = 32; off; off >>= 1) s += __shfl_down(s, off, 64);
    if (lane == 0) out2[row] = s;
}

// ---- prep: plain f32 -> bf16 convert (8 elems/thread) ----
__global__ __launch_bounds__(256) void conv_bf16(const float* __restrict__ in,
                                                 unsigned short* __restrict__ outb,
                                                 int n8) {
    int i = blockIdx.x * 256 + threadIdx.x;
    if (i >= n8) return;
    const float4* p = (const float4*)in + (size_t)i * 2;
    float4 a = p[0], b = p[1];
    u16x8 o = { f2bf(a.x), f2bf(a.y), f2bf(a.z), f2bf(a.w),
                f2bf(b.x), f2bf(b.y), f2bf(b.z), f2bf(b.w) };
    *((u16x8*)outb + i) = o;
}

// ---- stage a 128x64 bf16 half-tile (512 threads, 2 gload_lds each) ----
// linear LDS dest; inverse swizzle on SOURCE; read-side chunk swizzle c^(r&7)
__device__ __forceinline__ void stage_half(const unsigned short* __restrict__ g,
                                           int ld, int rowBase, int k0,
                                           unsigned short* lds, int tid) {
#pragma unroll
    for (int i = 0; i < 2; i++) {
        int idx = i * 512 + tid;          // 16B-chunk index, 0..1023
        int row = idx >> 3;               // 8 chunks per 64-elem row
        int cc  = (idx & 7) ^ (row & 7);  // inverse swizzle on SOURCE
        const unsigned short* src = g + (size_t)(rowBase + row) * ld + k0 + cc * 8;
        unsigned short* dst = lds + (i * 512 + (tid & 448)) * 8; // wave-uniform base
        async16(src, dst);
    }
}

__device__ __forceinline__ bf16x8 frag(const unsigned short* T, int r, int kc) {
    return *(const bf16x8*)(T + r * 64 + ((kc ^ (r & 7)) << 3));
}

// ---- one K-tile u: 4 phases, 16 MFMA each; m201 stage plan:
//   PH0: read Q0 frags (12) | stage A-half0(u+1) -> Awr       | bar lgkm0 MFMA Q0 bar
//   PH1: read b1 (4)        | stage A-half1(u+1) -> Awr+8192  | bar lgkm0 MFMA Q1 bar
//   PH2: read a hi (8)      | stage B-half0(u+2) -> Bwr       | bar lgkm0 MFMA Q2 bar
//   PH3:                    | stage B-half1(u+2) -> Bwr+8192  | vmcnt bar MFMA Q3 bar
// Region safety: A(u+1) overwrites tile u-1's A (consumed); B(u+2) overwrites
// tile u's B region after its last read (PH1), barrier-separated.
// vmcnt(4) leaves only B(u+2)'s 4 loads in flight; guarantees tile u+1 landed.
__device__ __forceinline__ void ktile(const unsigned short* __restrict__ Ard,
                                      const unsigned short* __restrict__ Brd,
                                      unsigned short* __restrict__ Awr,
                                      unsigned short* __restrict__ Bwr,
                                      const unsigned short* __restrict__ gA, int lda, int aRow0,
                                      const unsigned short* __restrict__ gB, int ldb, int bRow0,
                                      int kA, int kB, bool stageA, bool stageB,
                                      f32x4 (&acc)[8][4], int tid, int l, int AR, int BC) {
    const int lr = l & 15, hi = l >> 4;
    bf16x8 a[4][2], b0[2][2], b1[2][2];

    // ---- PH0 ----
#pragma unroll
    for (int m = 0; m < 4; m++) { int r = AR + m * 16 + lr;
#pragma unroll
        for (int kk = 0; kk < 2; kk++) a[m][kk] = frag(Ard, r, kk * 4 + hi); }
#pragma unroll
    for (int n = 0; n < 2; n++) { int r = BC + n * 16 + lr;
#pragma unroll
        for (int kk = 0; kk < 2; kk++) b0[n][kk] = frag(Brd, r, kk * 4 + hi); }
    if (stageA) stage_half(gA, lda, aRow0, kA, Awr, tid);
    asm volatile("s_waitcnt lgkmcnt(8)" ::: "memory");
    BAR(); LGKM0();
    __builtin_amdgcn_s_setprio(1);
#pragma unroll
    for (int kk = 0; kk < 2; kk++)
#pragma unroll
        for (int m = 0; m < 4; m++)
#pragma unroll
            for (int n = 0; n < 2; n++) MFMA(acc[m][n], a[m][kk], b0[n][kk]);
    __builtin_amdgcn_s_setprio(0);
    BAR();

    // ---- PH1 ----
#pragma unroll
    for (int n = 0; n < 2; n++) { int r = BC + (n + 2) * 16 + lr;
#pragma unroll
        for (int kk = 0; kk < 2; kk++) b1[n][kk] = frag(Brd, r, kk * 4 + hi); }
    if (stageA) stage_half(gA, lda, aRow0 + 128, kA, Awr + 8192, tid);
    BAR(); LGKM0();
    __builtin_amdgcn_s_setprio(1);
#pragma unroll
    for (int kk = 0; kk < 2; kk++)
#pragma unroll
        for (int m = 0; m < 4; m++)
#pragma unroll
            for (int n = 0; n < 2; n++) MFMA(acc[m][2 + n], a[m][kk], b1[n][kk]);
    __builtin_amdgcn_s_setprio(0);
    BAR();

    // ---- PH2 ----
#pragma unroll
    for (int m = 0; m < 4; m++) { int r = AR + (m + 4) * 16 + lr;
#pragma unroll
        for (int kk = 0; kk < 2; kk++) a[m][kk] = frag(Ard, r, kk * 4 + hi); }
    if (stageB) stage_half(gB, ldb, bRow0, kB, Bwr, tid);
    BAR(); LGKM0();
    __builtin_amdgcn_s_setprio(1);
#pragma unroll
    for (int kk = 0; kk < 2; kk++)
#pragma unroll
        for (int m = 0; m < 4; m++)
#pragma unroll
            for (int n = 0; n < 2; n++) MFMA(acc[4 + m][n], a[m][kk], b0[n][kk]);
    __builtin_amdgcn_s_setprio(0);
    BAR();

    // ---- PH3 ----
    if (stageB) {
        stage_half(gB, ldb, bRow0 + 128, kB, Bwr + 8192, tid);
        asm volatile("s_waitcnt vmcnt(4)" ::: "memory");   // tile u+1 landed; B(u+2) flies
    } else {
        asm volatile("s_waitcnt vmcnt(0)" ::: "memory");   // tail: exact drain
    }
    BAR();
    __builtin_amdgcn_s_setprio(1);
#pragma unroll
    for (int kk = 0; kk < 2; kk++)
#pragma unroll
        for (int m = 0; m < 4; m++)
#pragma unroll
            for (int n = 0; n < 2; n++) MFMA(acc[4 + m][2 + n], a[m][kk], b1[n][kk]);
    __builtin_amdgcn_s_setprio(0);
    BAR();
}

__device__ __forceinline__ void gemm_core(const unsigned short* __restrict__ gA, int lda, int aRow0,
                                          const unsigned short* __restrict__ gB, int ldb, int bRow0,
                                          int nt, f32x4 (&acc)[8][4],
                                          unsigned short (&As)[2][16384],
                                          unsigned short (&Bs)[2][16384],
                                          int tid, int l, int AR, int BC) {
    // prologue: A(0), B(0) fully; B(1); A(1) staged by tile0's PH0/PH1
    stage_half(gA, lda, aRow0,       0,  As[0],        tid);
    stage_half(gA, lda, aRow0 + 128, 0,  As[0] + 8192, tid);
    stage_half(gB, ldb, bRow0,       0,  Bs[0],        tid);
    stage_half(gB, ldb, bRow0 + 128, 0,  Bs[0] + 8192, tid);
    stage_half(gB, ldb, bRow0,       64, Bs[1],        tid);
    stage_half(gB, ldb, bRow0 + 128, 64, Bs[1] + 8192, tid);
    asm volatile("s_waitcnt vmcnt(4)" ::: "memory");   // tile0 landed; B(1) in flight
    __builtin_amdgcn_s_barrier();

    for (int u = 0; u < nt; u += 2) {
        // even tile u: read buf0; stage A(u+1)->buf1, B(u+2)->buf0
        ktile(As[0], Bs[0], As[1], Bs[0], gA, lda, aRow0, gB, ldb, bRow0,
              (u + 1) * 64, (u + 2) * 64, u + 1 < nt, u + 2 < nt,
              acc, tid, l, AR, BC);
        // odd tile u+1: read buf1; stage A(u+2)->buf0, B(u+3)->buf1
        ktile(As[1], Bs[1], As[0], Bs[1], gA, lda, aRow0, gB, ldb, bRow0,
              (u + 2) * 64, (u + 3) * 64, u + 2 < nt, u + 3 < nt,
              acc, tid, l, AR, BC);
    }
}

// ---- GEMM1: xc = x @ centers^T ; epilogue -> phi bf16 ----
__global__ __launch_bounds__(512) void gemm1_kernel(const unsigned short* __restrict__ xb,
                                                    const unsigned short* __restrict__ cb,
                                                    const float* __restrict__ x2,
                                                    const float* __restrict__ c2,
                                                    const int* __restrict__ sigp,
                                                    unsigned short* __restrict__ phi) {
    __shared__ unsigned short As[2][16384];
    __shared__ unsigned short Bs[2][16384];
    int tid = threadIdx.x;
    // XCD-chunked swizzle (nwg = 1024, %8 == 0)
    int nwg = gridDim.x, cpx = nwg >> 3, bid = blockIdx.x;
    int nb = (bid & 7) * cpx + (bid >> 3);
    const int nbx = C_DIM / 256;
    int aRow0 = (nb / nbx) * 256, bRow0 = (nb % nbx) * 256;
    int l = tid & 63, wid = tid >> 6;
    int AR = (wid >> 2) * 128, BC = (wid & 3) * 64;

    f32x4 acc[8][4] = {};
    gemm_core(xb, D_DIM, aRow0, cb, D_DIM, bRow0, D_DIM / 64, acc, As, Bs, tid, l, AR, BC);

    float inv2s = 0.5f / read_sigma(sigp);
    int lr = l & 15, hi = l >> 4;
#pragma unroll
    for (int m = 0; m < 8; m++) {
#pragma unroll
        for (int j = 0; j < 4; j++) {
            int row = aRow0 + AR + m * 16 + hi * 4 + j;
            float xr = x2[row];
#pragma unroll
            for (int n = 0; n < 4; n++) {
                int col = bRow0 + BC + n * 16 + lr;
                float d2 = fmaxf(xr + c2[col] - 2.0f * acc[m][n][j], 0.0f);
                float ph = __expf(-__builtin_sqrtf(d2) * inv2s);
                phi[(size_t)row * C_DIM + col] = f2bf(ph);
            }
        }
    }
}

// ---- GEMM2: out = sigmoid(phi @ W1^T + b1) ----
__global__ __launch_bounds__(512) void gemm2_kernel(const unsigned short* __restrict__ phi,
                                                    const unsigned short* __restrict__ wb,
                                                    const float* __restrict__ b1,
                                                    float* __restrict__ out) {
    __shared__ unsigned short As[2][16384];
    __shared__ unsigned short Bs[2][16384];
    int tid = threadIdx.x;
    // XCD-chunked swizzle (nwg = 256, %8 == 0)
    int nwg = gridDim.x, cpx = nwg >> 3, bid = blockIdx.x;
    int nb = (bid & 7) * cpx + (bid >> 3);
    const int nbx = H_DIM / 256;
    int aRow0 = (nb / nbx) * 256, bRow0 = (nb % nbx) * 256;
    int l = tid & 63, wid = tid >> 6;
    int AR = (wid >> 2) * 128, BC = (wid & 3) * 64;

    f32x4 acc[8][4] = {};
    gemm_core(phi, C_DIM, aRow0, wb, C_DIM, bRow0, C_DIM / 64, acc, As, Bs, tid, l, AR, BC);

    int lr = l & 15, hi = l >> 4;
#pragma unroll
    for (int m = 0; m < 8; m++) {
#pragma unroll
        for (int j = 0; j < 4; j++) {
            int row = aRow0 + AR + m * 16 + hi * 4 + j;
#pragma unroll
            for (int n = 0; n < 4; n++) {
                int col = bRow0 + BC + n * 16 + lr;
                float z = acc[m][n][j] + b1[col];
                out[(size_t)row * H_DIM + col] = 1.0f / (1.0f + __expf(-z));
            }
        }
    }
}

extern "C" void kernel_launch(void* const* d_in, const int* in_sizes, int n_in,
                              void* d_out, int out_size, void* d_ws, size_t ws_size,
                              hipStream_t stream) {
    const float* x       = (const float*)d_in[0];
    const float* centers = (const float*)d_in[1];
    const float* W1      = (const float*)d_in[2];
    const float* b1      = (const float*)d_in[3];
    const int*   sig     = (const int*)d_in[4];
    float* out = (float*)d_out;

    char* ws = (char*)d_ws;
    unsigned short* phi = (unsigned short*)(ws);                 // 16384*4096*2 = 134217728
    unsigned short* xb  = (unsigned short*)(ws + 134217728);     // 16384*512*2  = 16777216
    unsigned short* cb  = (unsigned short*)(ws + 150994944);     // 4096*512*2   = 4194304
    unsigned short* wb  = (unsigned short*)(ws + 155189248);     // 1024*4096*2  = 8388608
    float* x2 = (float*)(ws + 163577856);                        // 16384*4
    float* c2 = (float*)(ws + 163643392);                        // 4096*4

    prep_rows<<<B_ROWS / 4, 256, 0, stream>>>(x, xb, x2);
    prep_rows<<<C_DIM / 4, 256, 0, stream>>>(centers, cb, c2);
    conv_bf16<<<(H_DIM * C_DIM / 8 + 255) / 256, 256, 0, stream>>>(W1, wb, H_DIM * C_DIM / 8);

    gemm1_kernel<<<(B_ROWS / 256) * (C_DIM / 256), 512, 0, stream>>>(xb, cb, x2, c2, sig, phi);
    gemm2_kernel<<<(B_ROWS / 256) * (H_DIM / 256), 512, 0, stream>>>(phi, wb, b1, out);
}